// Round 3
// baseline (112.790 us; speedup 1.0000x reference)
//
#include <hip/hip_runtime.h>

typedef _Float16 half4 __attribute__((ext_vector_type(4)));
typedef _Float16 half8 __attribute__((ext_vector_type(8)));
typedef float    f32x4 __attribute__((ext_vector_type(4)));

#define MFMA16(a,b,c) __builtin_amdgcn_mfma_f32_16x16x16f16((a),(b),(c),0,0,0)

static constexpr int N_NODES  = 200000;
static constexpr int N_GRAPHS = 64;
static constexpr int SGPG     = 128;               // 32-node supergroups per graph (max 4096 nodes/graph)
static constexpr int TOTAL_SG = N_GRAPHS * SGPG;   // 8192

// ---- workspace byte offsets ----
static constexpr size_t WS_ZWT    = 0;        // [64][128][16] f16 : (z@W1)^T per graph, d-major k-inner
static constexpr size_t WS_W2T    = 262144;   // [128][128] f16    : W2T[d_out][d_in]
static constexpr size_t WS_WHT    = 294912;   // [16][128]  f16    : rows 0..3 = [Wp|Wv]^T, rest zero
static constexpr size_t WS_GSTART = 299008;   // 65 int

// ---- LDS layout (37,888 B/block -> 4 blocks/CU) ----
// a2 pairs : [8 mo][4 tp][64 lane] x 16B = 32768    (frag pair t=2tp,2tp+1 for lane)
// a3       : [8 t][64 lane] x 8B        =  4096
// b1       : 128 f32                    =   512
// b2       : 128 f32                    =   512

// ---------------- single prep kernel ----------------
__global__ __launch_bounds__(256) void gnn_prep(
    const int* __restrict__ batch,
    const float* __restrict__ z,
    const float* __restrict__ W1,
    const float* __restrict__ W2,
    const float* __restrict__ Wp,
    const float* __restrict__ Wv,
    int* __restrict__ gstart,
    _Float16* __restrict__ zwt,
    _Float16* __restrict__ w2t,
    _Float16* __restrict__ wht)
{
    const int b = blockIdx.x, t = threadIdx.x;
    if (b < 782) {
        const int i = b * 256 + t;
        if (i < N_NODES) {
            const int bi   = batch[i];
            const int prev = (i == 0) ? -1 : batch[i - 1];
            if (bi != prev)
                for (int g = prev + 1; g <= bi; ++g) gstart[g] = i;
            if (i == N_NODES - 1)
                for (int g = bi + 1; g <= N_GRAPHS; ++g) gstart[g] = N_NODES;
        }
    } else if (b < 846) {
        const int e = (b - 782) * 256 + t;
        const int n = e >> 7, kk = e & 127;
        w2t[e] = (_Float16)W2[kk * 128 + n];
    } else if (b < 854) {
        const int e = (b - 846) * 256 + t;
        const int j = e >> 7, d = e & 127;
        float v = 0.f;
        if (j < 2)      v = Wp[d * 2 + j];
        else if (j < 4) v = Wv[d * 2 + (j - 2)];
        wht[e] = (_Float16)v;
    } else {
        const int p = (b - 854) * 2 + (t >> 7);
        const int g = p >> 4, k = p & 15, d = t & 127;
        const float* zr = z + (g * 16 + k) * 128;
        float a0 = 0.f, a1 = 0.f, a2 = 0.f, a3 = 0.f;
#pragma unroll 8
        for (int c = 0; c < 128; c += 4) {
            a0 += zr[c    ] * W1[(c    ) * 128 + d];
            a1 += zr[c + 1] * W1[(c + 1) * 128 + d];
            a2 += zr[c + 2] * W1[(c + 2) * 128 + d];
            a3 += zr[c + 3] * W1[(c + 3) * 128 + d];
        }
        zwt[(g * 128 + d) * 16 + k] = (_Float16)((a0 + a1) + (a2 + a3));
    }
}

__device__ inline float fast_tanh(float x) {
    x = fminf(fmaxf(x, -15.f), 15.f);
    const float e = __expf(2.f * x);
    return (e - 1.f) / (e + 1.f);
}

__device__ __forceinline__ half4 cvt4(f32x4 v) {
    half4 r;
    r[0] = (_Float16)v[0]; r[1] = (_Float16)v[1];
    r[2] = (_Float16)v[2]; r[3] = (_Float16)v[3];
    return r;
}

// predicated load of the two 16-node s-tiles for one supergroup (zeros past end)
__device__ __forceinline__ void load_s(const float* __restrict__ s,
                                       int base, int ge, int n16, int quad,
                                       f32x4& a, f32x4& b)
{
    const f32x4 z4 = {0.f, 0.f, 0.f, 0.f};
    a = z4; b = z4;
    if (base + n16 < ge)      a = *(const f32x4*)(s + (base + n16) * 16 + quad * 4);
    if (base + 16 + n16 < ge) b = *(const f32x4*)(s + (base + 16 + n16) * 16 + quad * 4);
}

// full per-supergroup compute: GEMM1'(+relu) -> GEMM2'(+relu) -> head -> store
__device__ __forceinline__ void compute_sg(
    int g, int base, int ge,
    half4 bsA, half4 bsB,
    const _Float16* __restrict__ zwt,
    const half8* a2l, const half4* a3l,
    const float* b1l, const float* b2l,
    f32x4 c3init, float* __restrict__ out,
    int lane, int n16, int quad)
{
    const int nodeA = base + n16;
    const int nodeB = base + 16 + n16;
    const bool vA = nodeA < ge;
    const bool vB = nodeB < ge;

    // GEMM1' + relu (bias via C-init); h1 frags feed GEMM2' directly
    const _Float16* zg = zwt + g * 2048;
    half4 h1a[8], h1b[8];
#pragma unroll
    for (int mt = 0; mt < 8; ++mt) {
        const half4 a1 = *(const half4*)(zg + (mt * 16 + n16) * 16 + quad * 4);
        const f32x4 cb = *(const f32x4*)(b1l + mt * 16 + quad * 4);   // LDS broadcast
        const f32x4 accA = MFMA16(a1, bsA, cb);
        const f32x4 accB = MFMA16(a1, bsB, cb);
#pragma unroll
        for (int i = 0; i < 4; ++i) {
            h1a[mt][i] = (_Float16)fmaxf(accA[i], 0.f);
            h1b[mt][i] = (_Float16)fmaxf(accB[i], 0.f);
        }
    }

    // GEMM2' + relu + head, weights from LDS (each frag-pair feeds 4 MFMAs)
    f32x4 acc3a = c3init, acc3b = c3init;
    __builtin_amdgcn_s_setprio(1);      // T5: favor the MFMA-dense region
#pragma unroll
    for (int mo = 0; mo < 8; ++mo) {
        const f32x4 cb = *(const f32x4*)(b2l + mo * 16 + quad * 4);
        f32x4 a2a = cb, a2b = cb;
#pragma unroll
        for (int tp = 0; tp < 4; ++tp) {
            const half8 w = a2l[(mo * 4 + tp) * 64 + lane];
            const half4 wlo = {w[0], w[1], w[2], w[3]};
            const half4 whi = {w[4], w[5], w[6], w[7]};
            a2a = MFMA16(wlo, h1a[tp * 2], a2a);
            a2a = MFMA16(whi, h1a[tp * 2 + 1], a2a);
            a2b = MFMA16(wlo, h1b[tp * 2], a2b);
            a2b = MFMA16(whi, h1b[tp * 2 + 1], a2b);
        }
        half4 h2a, h2b;
#pragma unroll
        for (int i = 0; i < 4; ++i) {
            h2a[i] = (_Float16)fmaxf(a2a[i], 0.f);
            h2b[i] = (_Float16)fmaxf(a2b[i], 0.f);
        }
        const half4 w3 = a3l[mo * 64 + lane];
        acc3a = MFMA16(w3, h2a, acc3a);
        acc3b = MFMA16(w3, h2b, acc3b);
    }
    __builtin_amdgcn_s_setprio(0);

    if (quad == 0) {
        if (vA) {
            f32x4 o;
            o[0] = fast_tanh(acc3a[0]); o[1] = fast_tanh(acc3a[1]);
            o[2] = acc3a[2];            o[3] = acc3a[3];
            *(f32x4*)(out + nodeA * 4) = o;
        }
        if (vB) {
            f32x4 o;
            o[0] = fast_tanh(acc3b[0]); o[1] = fast_tanh(acc3b[1]);
            o[2] = acc3b[2];            o[3] = acc3b[3];
            *(f32x4*)(out + nodeB * 4) = o;
        }
    }
}

// ---------------- main ----------------
__global__ __launch_bounds__(256, 4) void gnn_main(
    const float* __restrict__ s,
    const float* __restrict__ b1,
    const float* __restrict__ b2,
    const float* __restrict__ bp,
    const float* __restrict__ bv,
    const _Float16* __restrict__ zwt,
    const _Float16* __restrict__ w2t,
    const _Float16* __restrict__ wht,
    const int* __restrict__ gstart,
    float* __restrict__ out)
{
    __shared__ char lds[37888];
    half8* a2l = (half8*)lds;                 // [mo*4+tp][lane]
    half4* a3l = (half4*)(lds + 32768);       // [t][lane]
    float* b1l = (float*)(lds + 36864);
    float* b2l = (float*)(lds + 37376);

    const int tid  = threadIdx.x;
    const int lane = tid & 63;
    const int n16  = lane & 15;
    const int quad = lane >> 4;

    // ---- stage weights into LDS ----
#pragma unroll
    for (int r = 0; r < 8; ++r) {
        const int e  = r * 256 + tid;         // 0..2047
        const int mo = e >> 8, tp = (e >> 6) & 3, ll = e & 63;
        const int nn = ll & 15, qq = ll >> 4;
        const _Float16* srcp = w2t + (mo * 16 + nn) * 128 + tp * 32 + qq * 4;
        half8 v;
        *(half4*)&v     = *(const half4*)srcp;        // t = 2tp
        *((half4*)&v+1) = *(const half4*)(srcp + 16); // t = 2tp+1
        a2l[e] = v;
    }
    {
        const int e = tid;                    // 0..255 -> a3 first half; +256 second
#pragma unroll
        for (int r = 0; r < 2; ++r) {
            const int ee = r * 256 + e;       // 0..511 : [t][lane]
            const int tt = ee >> 6, ll = ee & 63;
            const int nn = ll & 15, qq = ll >> 4;
            a3l[ee] = *(const half4*)(wht + nn * 128 + tt * 16 + qq * 4);
        }
        if (tid < 128)      b1l[tid] = b1[tid];
        else                b2l[tid - 128] = b2[tid - 128];
    }
    __syncthreads();

    const float bp0 = bp[0], bp1 = bp[1], bv0 = bv[0], bv1 = bv[1];
    f32x4 c3init = {0.f, 0.f, 0.f, 0.f};
    if (quad == 0) { c3init[0] = bp0; c3init[1] = bp1; c3init[2] = bv0; c3init[3] = bv1; }

    const int wid = blockIdx.x * 4 + (tid >> 6);
    const int nw  = gridDim.x * 4;            // 4096 at grid=1024 -> exactly 2 sg per wave

    // ---- 2-deep pipeline over the wave's two supergroups ----
    const int sg0 = wid;
    const int sg1 = wid + nw;

    const int g0 = sg0 >> 7;
    const int gs0 = gstart[g0], ge0 = gstart[g0 + 1];
    const int base0 = gs0 + (sg0 & 127) * 32;
    const bool act0 = base0 < ge0;

    const bool in1 = sg1 < TOTAL_SG;
    const int g1 = in1 ? (sg1 >> 7) : 0;
    const int gs1 = in1 ? gstart[g1] : 0;
    const int ge1 = in1 ? gstart[g1 + 1] : 0;
    const int base1 = gs1 + (sg1 & 127) * 32;
    const bool act1 = in1 && (base1 < ge1);

    // issue ALL s-tile loads up front (T14 issue-early / consume-late)
    f32x4 sA0, sB0, sA1, sB1;
    const f32x4 z4 = {0.f, 0.f, 0.f, 0.f};
    sA0 = z4; sB0 = z4; sA1 = z4; sB1 = z4;
    if (act0) load_s(s, base0, ge0, n16, quad, sA0, sB0);
    if (act1) load_s(s, base1, ge1, n16, quad, sA1, sB1);

    if (act0) {
        compute_sg(g0, base0, ge0, cvt4(sA0), cvt4(sB0),
                   zwt, a2l, a3l, b1l, b2l, c3init, out, lane, n16, quad);
    }
    if (act1) {
        compute_sg(g1, base1, ge1, cvt4(sA1), cvt4(sB1),
                   zwt, a2l, a3l, b1l, b2l, c3init, out, lane, n16, quad);
    }

    // safety net if grid ever shrinks below 1024 (zero iterations at grid=1024)
    for (int sgi = wid + 2 * nw; sgi < TOTAL_SG; sgi += nw) {
        const int g    = sgi >> 7;
        const int gs   = gstart[g];
        const int ge   = gstart[g + 1];
        const int base = gs + (sgi & 127) * 32;
        if (base >= ge) continue;
        f32x4 sa, sb;
        load_s(s, base, ge, n16, quad, sa, sb);
        compute_sg(g, base, ge, cvt4(sa), cvt4(sb),
                   zwt, a2l, a3l, b1l, b2l, c3init, out, lane, n16, quad);
    }
}

extern "C" void kernel_launch(void* const* d_in, const int* in_sizes, int n_in,
                              void* d_out, int out_size, void* d_ws, size_t ws_size,
                              hipStream_t stream)
{
    const float* z     = (const float*)d_in[0];
    const float* s     = (const float*)d_in[1];
    const int*   batch = (const int*)d_in[2];
    const float* W1    = (const float*)d_in[3];
    const float* b1    = (const float*)d_in[4];
    const float* W2    = (const float*)d_in[5];
    const float* b2    = (const float*)d_in[6];
    const float* Wp    = (const float*)d_in[7];
    const float* bp    = (const float*)d_in[8];
    const float* Wv    = (const float*)d_in[9];
    const float* bv    = (const float*)d_in[10];
    float* out = (float*)d_out;

    char* w = (char*)d_ws;
    _Float16* zwt = (_Float16*)(w + WS_ZWT);
    _Float16* w2t = (_Float16*)(w + WS_W2T);
    _Float16* wht = (_Float16*)(w + WS_WHT);
    int* gstart   = (int*)(w + WS_GSTART);

    hipLaunchKernelGGL(gnn_prep, dim3(1366), dim3(256), 0, stream,
                       batch, z, W1, W2, Wp, Wv, gstart, zwt, w2t, wht);
    hipLaunchKernelGGL(gnn_main, dim3(1024), dim3(256), 0, stream,
                       s, b1, b2, bp, bv, zwt, w2t, wht, gstart, out);
}

// Round 7
// 111.138 us; speedup vs baseline: 1.0149x; 1.0149x over previous
//
#include <hip/hip_runtime.h>

typedef _Float16 half4 __attribute__((ext_vector_type(4)));
typedef _Float16 half8 __attribute__((ext_vector_type(8)));
typedef float    f32x4 __attribute__((ext_vector_type(4)));

#define MFMA16(a,b,c) __builtin_amdgcn_mfma_f32_16x16x16f16((a),(b),(c),0,0,0)
#define MFMA32(a,b,c) __builtin_amdgcn_mfma_f32_16x16x32_f16((a),(b),(c),0,0,0)

static constexpr int N_NODES  = 200000;
static constexpr int N_GRAPHS = 64;
static constexpr int SGPG     = 128;               // 32-node supergroups per graph (max 4096 nodes/graph)
static constexpr int TOTAL_SG = N_GRAPHS * SGPG;   // 8192

// ---- workspace byte offsets ----
static constexpr size_t WS_ZWT    = 0;        // [64][128][16] f16 : (z@W1)^T per graph, d-major k-inner
static constexpr size_t WS_W2T    = 262144;   // [128][128] f16    : W2T[d_out][d_in]
static constexpr size_t WS_WHT    = 294912;   // [16][128]  f16    : rows 0..3 = [Wp|Wv]^T, rest zero
static constexpr size_t WS_GSTART = 299008;   // 65 int

// ---- LDS layout (37,888 B/block -> 4 blocks/CU) ----
// a2 pairs : [8 mo][4 tp][64 lane] x 16B = 32768    (k-permuted half8 = A-frag of 16x16x32)
// a3       : [8 t][64 lane] x 8B        =  4096
// b1       : 128 f32                    =   512
// b2       : 128 f32                    =   512

// ---------------- single prep kernel ----------------
__global__ __launch_bounds__(256) void gnn_prep(
    const int* __restrict__ batch,
    const float* __restrict__ z,
    const float* __restrict__ W1,
    const float* __restrict__ W2,
    const float* __restrict__ Wp,
    const float* __restrict__ Wv,
    int* __restrict__ gstart,
    _Float16* __restrict__ zwt,
    _Float16* __restrict__ w2t,
    _Float16* __restrict__ wht)
{
    const int b = blockIdx.x, t = threadIdx.x;
    if (b < 782) {
        const int i = b * 256 + t;
        if (i < N_NODES) {
            const int bi   = batch[i];
            const int prev = (i == 0) ? -1 : batch[i - 1];
            if (bi != prev)
                for (int g = prev + 1; g <= bi; ++g) gstart[g] = i;
            if (i == N_NODES - 1)
                for (int g = bi + 1; g <= N_GRAPHS; ++g) gstart[g] = N_NODES;
        }
    } else if (b < 846) {
        const int e = (b - 782) * 256 + t;
        const int n = e >> 7, kk = e & 127;
        w2t[e] = (_Float16)W2[kk * 128 + n];
    } else if (b < 854) {
        const int e = (b - 846) * 256 + t;
        const int j = e >> 7, d = e & 127;
        float v = 0.f;
        if (j < 2)      v = Wp[d * 2 + j];
        else if (j < 4) v = Wv[d * 2 + (j - 2)];
        wht[e] = (_Float16)v;
    } else {
        const int p = (b - 854) * 2 + (t >> 7);
        const int g = p >> 4, k = p & 15, d = t & 127;
        const float* zr = z + (g * 16 + k) * 128;
        float a0 = 0.f, a1 = 0.f, a2 = 0.f, a3 = 0.f;
#pragma unroll 8
        for (int c = 0; c < 128; c += 4) {
            a0 += zr[c    ] * W1[(c    ) * 128 + d];
            a1 += zr[c + 1] * W1[(c + 1) * 128 + d];
            a2 += zr[c + 2] * W1[(c + 2) * 128 + d];
            a3 += zr[c + 3] * W1[(c + 3) * 128 + d];
        }
        zwt[(g * 128 + d) * 16 + k] = (_Float16)((a0 + a1) + (a2 + a3));
    }
}

__device__ inline float fast_tanh(float x) {
    x = fminf(fmaxf(x, -15.f), 15.f);
    const float e = __expf(2.f * x);
    return (e - 1.f) / (e + 1.f);
}

__device__ __forceinline__ half4 cvt4(f32x4 v) {
    half4 r;
    r[0] = (_Float16)v[0]; r[1] = (_Float16)v[1];
    r[2] = (_Float16)v[2]; r[3] = (_Float16)v[3];
    return r;
}

// predicated load of the two 16-node s-tiles for one supergroup (zeros past end)
__device__ __forceinline__ void load_s(const float* __restrict__ s,
                                       int base, int ge, int n16, int quad,
                                       f32x4& a, f32x4& b)
{
    const f32x4 z4 = {0.f, 0.f, 0.f, 0.f};
    a = z4; b = z4;
    if (base + n16 < ge)      a = *(const f32x4*)(s + (base + n16) * 16 + quad * 4);
    if (base + 16 + n16 < ge) b = *(const f32x4*)(s + (base + 16 + n16) * 16 + quad * 4);
}

// full per-supergroup compute: GEMM1'(+relu) -> GEMM2'(K=32 native) -> head -> store
__device__ __forceinline__ void compute_sg(
    int g, int base, int ge,
    half4 bsA, half4 bsB,
    const _Float16* __restrict__ zwt,
    const half8* a2l, const half4* a3l,
    const float* b1l, const float* b2l,
    f32x4 c3init, float* __restrict__ out,
    int lane, int n16, int quad)
{
    const int nodeA = base + n16;
    const int nodeB = base + 16 + n16;
    const bool vA = nodeA < ge;
    const bool vB = nodeB < ge;

    // GEMM1' + relu (bias via C-init).
    // h1 packed as half8 per tp: elems 0-3 from mt=2tp (d = tp*32+quad*4+i),
    // elems 4-7 from mt=2tp+1 (d = tp*32+16+quad*4+i) — the SAME k-permutation
    // a2l carries on the A side, so it feeds 16x16x32 B-frags directly.
    const _Float16* zg = zwt + g * 2048;
    half8 h1a8[4], h1b8[4];
#pragma unroll
    for (int mt = 0; mt < 8; ++mt) {
        const half4 a1 = *(const half4*)(zg + (mt * 16 + n16) * 16 + quad * 4);
        const f32x4 cb = *(const f32x4*)(b1l + mt * 16 + quad * 4);   // LDS broadcast
        const f32x4 accA = MFMA16(a1, bsA, cb);
        const f32x4 accB = MFMA16(a1, bsB, cb);
        const int tp  = mt >> 1;
        const int off = (mt & 1) * 4;
#pragma unroll
        for (int i = 0; i < 4; ++i) {
            h1a8[tp][off + i] = (_Float16)fmaxf(accA[i], 0.f);
            h1b8[tp][off + i] = (_Float16)fmaxf(accB[i], 0.f);
        }
    }

    // GEMM2' (native 16x16x32, k-permutation cancels on A/B) + relu + head
    f32x4 acc3a = c3init, acc3b = c3init;
    __builtin_amdgcn_s_setprio(1);      // T5: favor the MFMA-dense region
#pragma unroll
    for (int mo = 0; mo < 8; ++mo) {
        const f32x4 cb = *(const f32x4*)(b2l + mo * 16 + quad * 4);
        f32x4 a2a = cb, a2b = cb;
#pragma unroll
        for (int tp = 0; tp < 4; ++tp) {
            const half8 w = a2l[(mo * 4 + tp) * 64 + lane];
            a2a = MFMA32(w, h1a8[tp], a2a);
            a2b = MFMA32(w, h1b8[tp], a2b);
        }
        half4 h2a, h2b;
#pragma unroll
        for (int i = 0; i < 4; ++i) {
            h2a[i] = (_Float16)fmaxf(a2a[i], 0.f);
            h2b[i] = (_Float16)fmaxf(a2b[i], 0.f);
        }
        const half4 w3 = a3l[mo * 64 + lane];
        acc3a = MFMA16(w3, h2a, acc3a);
        acc3b = MFMA16(w3, h2b, acc3b);
    }
    __builtin_amdgcn_s_setprio(0);

    if (quad == 0) {
        if (vA) {
            f32x4 o;
            o[0] = fast_tanh(acc3a[0]); o[1] = fast_tanh(acc3a[1]);
            o[2] = acc3a[2];            o[3] = acc3a[3];
            *(f32x4*)(out + nodeA * 4) = o;
        }
        if (vB) {
            f32x4 o;
            o[0] = fast_tanh(acc3b[0]); o[1] = fast_tanh(acc3b[1]);
            o[2] = acc3b[2];            o[3] = acc3b[3];
            *(f32x4*)(out + nodeB * 4) = o;
        }
    }
}

// ---------------- main ----------------
__global__ __launch_bounds__(256, 4) void gnn_main(
    const float* __restrict__ s,
    const float* __restrict__ b1,
    const float* __restrict__ b2,
    const float* __restrict__ bp,
    const float* __restrict__ bv,
    const _Float16* __restrict__ zwt,
    const _Float16* __restrict__ w2t,
    const _Float16* __restrict__ wht,
    const int* __restrict__ gstart,
    float* __restrict__ out)
{
    __shared__ char lds[37888];
    half8* a2l = (half8*)lds;                 // [mo*4+tp][lane]
    half4* a3l = (half4*)(lds + 32768);       // [t][lane]
    float* b1l = (float*)(lds + 36864);
    float* b2l = (float*)(lds + 37376);

    const int tid  = threadIdx.x;
    const int lane = tid & 63;
    const int n16  = lane & 15;
    const int quad = lane >> 4;

    // ---- stage weights into LDS ----
#pragma unroll
    for (int r = 0; r < 8; ++r) {
        const int e  = r * 256 + tid;         // 0..2047
        const int mo = e >> 8, tp = (e >> 6) & 3, ll = e & 63;
        const int nn = ll & 15, qq = ll >> 4;
        const _Float16* srcp = w2t + (mo * 16 + nn) * 128 + tp * 32 + qq * 4;
        half8 v;
        *(half4*)&v     = *(const half4*)srcp;        // k-slots j=0..3
        *((half4*)&v+1) = *(const half4*)(srcp + 16); // k-slots j=4..7
        a2l[e] = v;
    }
    {
        const int e = tid;                    // 0..255 -> a3 first half; +256 second
#pragma unroll
        for (int r = 0; r < 2; ++r) {
            const int ee = r * 256 + e;       // 0..511 : [t][lane]
            const int tt = ee >> 6, ll = ee & 63;
            const int nn = ll & 15, qq = ll >> 4;
            a3l[ee] = *(const half4*)(wht + nn * 128 + tt * 16 + qq * 4);
        }
        if (tid < 128)      b1l[tid] = b1[tid];
        else                b2l[tid - 128] = b2[tid - 128];
    }
    __syncthreads();

    const float bp0 = bp[0], bp1 = bp[1], bv0 = bv[0], bv1 = bv[1];
    f32x4 c3init = {0.f, 0.f, 0.f, 0.f};
    if (quad == 0) { c3init[0] = bp0; c3init[1] = bp1; c3init[2] = bv0; c3init[3] = bv1; }

    const int wid = blockIdx.x * 4 + (tid >> 6);
    const int nw  = gridDim.x * 4;            // 4096 at grid=1024 -> exactly 2 sg per wave

    // ---- 2-deep pipeline over the wave's two supergroups ----
    const int sg0 = wid;
    const int sg1 = wid + nw;

    const int g0 = sg0 >> 7;
    const int gs0 = gstart[g0], ge0 = gstart[g0 + 1];
    const int base0 = gs0 + (sg0 & 127) * 32;
    const bool act0 = base0 < ge0;

    const bool in1 = sg1 < TOTAL_SG;
    const int g1 = in1 ? (sg1 >> 7) : 0;
    const int gs1 = in1 ? gstart[g1] : 0;
    const int ge1 = in1 ? gstart[g1 + 1] : 0;
    const int base1 = gs1 + (sg1 & 127) * 32;
    const bool act1 = in1 && (base1 < ge1);

    // issue ALL s-tile loads up front (T14 issue-early / consume-late)
    f32x4 sA0, sB0, sA1, sB1;
    const f32x4 z4 = {0.f, 0.f, 0.f, 0.f};
    sA0 = z4; sB0 = z4; sA1 = z4; sB1 = z4;
    if (act0) load_s(s, base0, ge0, n16, quad, sA0, sB0);
    if (act1) load_s(s, base1, ge1, n16, quad, sA1, sB1);

    if (act0) {
        compute_sg(g0, base0, ge0, cvt4(sA0), cvt4(sB0),
                   zwt, a2l, a3l, b1l, b2l, c3init, out, lane, n16, quad);
    }
    if (act1) {
        compute_sg(g1, base1, ge1, cvt4(sA1), cvt4(sB1),
                   zwt, a2l, a3l, b1l, b2l, c3init, out, lane, n16, quad);
    }

    // safety net if grid ever shrinks below 1024 (zero iterations at grid=1024)
    for (int sgi = wid + 2 * nw; sgi < TOTAL_SG; sgi += nw) {
        const int g    = sgi >> 7;
        const int gs   = gstart[g];
        const int ge   = gstart[g + 1];
        const int base = gs + (sgi & 127) * 32;
        if (base >= ge) continue;
        f32x4 sa, sb;
        load_s(s, base, ge, n16, quad, sa, sb);
        compute_sg(g, base, ge, cvt4(sa), cvt4(sb),
                   zwt, a2l, a3l, b1l, b2l, c3init, out, lane, n16, quad);
    }
}

extern "C" void kernel_launch(void* const* d_in, const int* in_sizes, int n_in,
                              void* d_out, int out_size, void* d_ws, size_t ws_size,
                              hipStream_t stream)
{
    const float* z     = (const float*)d_in[0];
    const float* s     = (const float*)d_in[1];
    const int*   batch = (const int*)d_in[2];
    const float* W1    = (const float*)d_in[3];
    const float* b1    = (const float*)d_in[4];
    const float* W2    = (const float*)d_in[5];
    const float* b2    = (const float*)d_in[6];
    const float* Wp    = (const float*)d_in[7];
    const float* bp    = (const float*)d_in[8];
    const float* Wv    = (const float*)d_in[9];
    const float* bv    = (const float*)d_in[10];
    float* out = (float*)d_out;

    char* w = (char*)d_ws;
    _Float16* zwt = (_Float16*)(w + WS_ZWT);
    _Float16* w2t = (_Float16*)(w + WS_W2T);
    _Float16* wht = (_Float16*)(w + WS_WHT);
    int* gstart   = (int*)(w + WS_GSTART);

    hipLaunchKernelGGL(gnn_prep, dim3(1366), dim3(256), 0, stream,
                       batch, z, W1, W2, Wp, Wv, gstart, zwt, w2t, wht);
    hipLaunchKernelGGL(gnn_main, dim3(1024), dim3(256), 0, stream,
                       s, b1, b2, bp, bv, zwt, w2t, wht, gstart, out);
}